// Round 11
// baseline (430.458 us; speedup 1.0000x reference)
//
#include <hip/hip_runtime.h>

typedef __bf16 bf16_t;
typedef __bf16 bf16x2 __attribute__((ext_vector_type(2)));
typedef __bf16 bf16x4 __attribute__((ext_vector_type(4)));
typedef __bf16 bf16x8 __attribute__((ext_vector_type(8)));
typedef float  f32x4  __attribute__((ext_vector_type(4)));
typedef int    i32x4  __attribute__((ext_vector_type(4)));

#define NPIX 2048
#define NS   64
#define NK   8
#define NSAMP (NPIX*NS)          // 131072
#define NROWS (NSAMP*NK)         // 1048576
#define TROWS 64
#define NTILES (NROWS/TROWS)     // 16384
#define GRID   768               // 3 blocks/CU (LDS 52KB); guarded schedule (16384 % 1536 != 0)
#define NITG   11                // ceil(NTILES / (2*GRID)); loop runs 0..NITG inclusive (drain)
#define XSTR 104                 // 96 cols + 8 pad (bf16), rows 16B-aligned
#define HSTR 136                 // bf16 feat_s/AR rows (8 rows only now)
#define QSTR 144                 // i8 H1/H2/H3 rows: 16B-aligned, 36dw ≡ 4 mod 32 (2-way, free)

// packed bf16 weight fragment bases (in bf16x8 units) — unchanged
#define PK_W0 0
#define PK_W1 1536
#define PK_W2 3584
#define PK_WA 5632
#define PK_WR 6656
#define PK_TOT 7680

#define PKQ_OFF   122880         // byte offset of i8 W1/W2 packs in workspace
#define WS_AR_BYTES (122880 + 32768)   // ar after the 2x16KB i8 packs

// ---- quantization scales (S1/S2 validated R8/R9; S3 new for H3) ----
#define SW_Q 300.0f              // W1/W2 weight scale
#define S1_Q 62.0f               // H1 scale (folded into W0/b0)
#define S2_Q 87.0f               // H2 scale
#define S3_Q 76.0f               // H3 scale (range ±1.67, step 0.013)
#define DQ1S2 (S2_Q / (S1_Q * SW_Q))   // L1 acc -> S2 units (lrelu homogeneous)
#define DQ2S3 (S3_Q / (S2_Q * SW_Q))   // L2 acc -> S3 units (b2 pre-scaled by S3)
#define RMAGIC 12582912.f        // 1.5*2^23: +RMAGIC = RNE round, int8 in mantissa low byte

// ---------------------------------------------------------------------------
// bf16 pack (R9 verbatim; W0 pre-scaled by S1_Q)
// ---------------------------------------------------------------------------
__global__ void pack_weights(const float* __restrict__ W0, const float* __restrict__ W1,
                             const float* __restrict__ W2, const float* __restrict__ Wa0,
                             const float* __restrict__ Wr0, bf16_t* __restrict__ dst0) {
  int tid = blockIdx.x * blockDim.x + threadIdx.x;
  if (tid >= PK_TOT * 8) return;
  const float* src; bf16_t* dst; int e, KD, ND, KS; float scl = 1.f;
  if (tid < 12288)      { src = W0;  dst = dst0;         e = tid;         KD = 88;  ND = 128; KS = 3; scl = S1_Q; }
  else if (tid < 28672) { src = W1;  dst = dst0 + 12288; e = tid - 12288; KD = 128; ND = 128; KS = 4; }
  else if (tid < 45056) { src = W2;  dst = dst0 + 28672; e = tid - 28672; KD = 128; ND = 128; KS = 4; }
  else if (tid < 53248) { src = Wa0; dst = dst0 + 45056; e = tid - 45056; KD = 128; ND = 64;  KS = 4; }
  else                  { src = Wr0; dst = dst0 + 53248; e = tid - 53248; KD = 128; ND = 64;  KS = 4; }
  int j = e & 7, l = (e >> 3) & 63, f = e >> 9;
  int s = f % KS, t = f / KS;
  int row = s * 32 + (l >> 4) * 8 + j;
  int col = t * 16 + (l & 15);
  float v = (row < KD) ? src[row * ND + col] * scl : 0.f;
  dst[e] = (bf16_t)v;
}

// ---------------------------------------------------------------------------
// i8 pack for W1/W2 (R9 verbatim)
// ---------------------------------------------------------------------------
__global__ void pack_w12_i8(const float* __restrict__ W1, const float* __restrict__ W2,
                            char* __restrict__ dstq) {
  int tid = blockIdx.x * blockDim.x + threadIdx.x;
  if (tid >= 2 * 16384) return;
  const float* src = (tid < 16384) ? W1 : W2;
  int e = tid & 16383;
  int j = e & 15, l = (e >> 4) & 63, f = e >> 10;
  int s = f & 1, t = f >> 1;
  int k = s * 64 + ((l >> 4) << 4) + j;
  int c = t * 16 + (l & 15);
  int iv = (int)rintf(src[k * 128 + c] * SW_Q);
  iv = iv > 127 ? 127 : (iv < -127 ? -127 : iv);
  dstq[tid] = (char)iv;
}

__device__ __forceinline__ float lrelu(float v) { return fmaxf(v, 0.1f * v); }
__device__ __forceinline__ float sigmoidf(float x) { return 1.f / (1.f + __expf(-x)); }

// R9-proven scalar quant helpers (R10's packed rewrite failed numerically; reverted)
__device__ __forceinline__ float q8pre(float v) {
  float h = fmaxf(v, 0.1f * v);
  h = fminf(fmaxf(h, -127.f), 127.f);
  return h + RMAGIC;
}
__device__ __forceinline__ unsigned pack4(float r0, float r1, float r2, float r3) {
  unsigned t0 = __builtin_amdgcn_perm(__builtin_bit_cast(unsigned, r1),
                                      __builtin_bit_cast(unsigned, r0), 0x00000400u);
  unsigned t1 = __builtin_amdgcn_perm(__builtin_bit_cast(unsigned, r3),
                                      __builtin_bit_cast(unsigned, r2), 0x00000400u);
  return __builtin_amdgcn_perm(t1, t0, 0x05040100u);
}

// ---------------------------------------------------------------------------
// Round-17 (R11): OCCUPANCY 2->3 blocks/CU on the R9 champion.
// R9 counters: VALU 52 / LDS ~50 / MFMA 15 — no pipe saturated => latency-
// bound; R6 proved wave count matters. LDS diet to 52.0KB (<160/3):
//  * H3 -> i8 (sQ3, S3=76): L2Q epilogue mirrors the PROVEN L1Q scalar path
//    (S3 folded into DQ2/b2 via lrelu homogeneity); KRED reads u16+sext.
//  * sFS/sAR shrink to 8 rows: MFMA D-col j depends only on B-col j, so
//    cols 8..15 (discarded) can take zero-filled exec-masked loads.
//  * GRID=768 (3/CU), block-uniform monotone guards aC/bC/aP/bP replace the
//    exact-divide schedule; producer guard <=> consumer guard verified per
//    phase. __launch_bounds__(512,6).
// Everything else byte-identical to R9 (scalar epilogues, q8pre/pack4).
// ---------------------------------------------------------------------------
__global__ __launch_bounds__(512, 6)
void nerf_main(const float* __restrict__ map_xyz, const float* __restrict__ map_feat,
               const int* __restrict__ ind, const float* __restrict__ sample_xyz,
               const float* __restrict__ b0g, const float* __restrict__ b1g,
               const float* __restrict__ b2g, const float* __restrict__ ba0g,
               const float* __restrict__ wa1g, const float* __restrict__ ba1g,
               const float* __restrict__ br0g, const float* __restrict__ wr1g,
               const float* __restrict__ br1g, const bf16_t* __restrict__ wpack,
               float* __restrict__ ar_out)
{
  __shared__ __align__(16) bf16_t sX[TROWS * XSTR];     // X (bf16)            13312 B
  __shared__ __align__(16) char   sQ1[TROWS * QSTR];    // H1 (i8)              9216 B
  __shared__ __align__(16) char   sQ2[TROWS * QSTR];    // H2 (i8)              9216 B
  __shared__ __align__(16) char   sQ3[TROWS * QSTR];    // H3 (i8)              9216 B
  __shared__ __align__(16) bf16_t sFS[8 * HSTR];        // feat_s, 8 rows       2176 B
  __shared__ __align__(16) bf16_t sAR[8 * HSTR];        // [r|a], 8 rows        2176 B
  __shared__ __align__(16) bf16_t sFB[2048];            // finals A-frags       4096 B
  __shared__ __align__(16) float sWtA[TROWS], sWtB[TROWS];
  __shared__ float sWsA[8], sWsB[8];
  __shared__ __align__(16) float sB0[128], sB1[128], sB2[128], sBH[128], sFBv[4];

  const int tid = threadIdx.x;
  const int wid = tid >> 6, l = tid & 63;
  const int q = l >> 4, n = l & 15;
  const int sr = tid >> 3, sp = tid & 7;   // staging thread coords

  // ---- persistent weights: W0/heads bf16 A-frags, W1/W2 i8 A-frags ----
  const bf16x8* pk = (const bf16x8*)wpack;
  bf16x8 w0f[3], hdf[4];
#pragma unroll
  for (int s = 0; s < 3; s++) w0f[s] = pk[PK_W0 + (wid * 3 + s) * 64 + l];
#pragma unroll
  for (int s = 0; s < 4; s++)
    hdf[s] = pk[(wid < 4 ? PK_WA : PK_WR) + ((wid & 3) * 4 + s) * 64 + l];
  const i32x4* pq = (const i32x4*)((const char*)wpack + PKQ_OFF);
  i32x4 w1q[2], w2q[2];
#pragma unroll
  for (int s = 0; s < 2; s++) {
    w1q[s] = pq[(wid * 2 + s) * 64 + l];
    w2q[s] = pq[1024 + (wid * 2 + s) * 64 + l];
  }

  // ---- phase ops ----
  auto COMMIT = [&](int tile, bf16_t* X, float* wtbuf) {
    const int m = tile * TROWS + sr;
    const int idx = ind[m];
    const float4* fp = (const float4*)(map_feat + (size_t)idx * 64 + sp * 8);
    float4 f0 = fp[0], f1 = fp[1];
    bf16x8 v;
    v[0] = (bf16_t)f0.x; v[1] = (bf16_t)f0.y; v[2] = (bf16_t)f0.z; v[3] = (bf16_t)f0.w;
    v[4] = (bf16_t)f1.x; v[5] = (bf16_t)f1.y; v[6] = (bf16_t)f1.z; v[7] = (bf16_t)f1.w;
    *(bf16x8*)(X + sr * XSTR + sp * 8) = v;
    const int g = m >> 3;
    if (sp < 6) {
      const int d = sp >> 1;
      float o = sample_xyz[g * 3 + d] - map_xyz[idx * 3 + d];
      float s1 = __sinf(o), c1 = __cosf(o);
      float s2 = 2.f * s1 * c1, c2 = 1.f - 2.f * s1 * s1;
      float s4 = 2.f * s2 * c2, c4 = 1.f - 2.f * s2 * s2;
      float s8 = 2.f * s4 * c4, c8 = 1.f - 2.f * s4 * s4;
      bf16x4 e;
      if (sp & 1) { e[0] = (bf16_t)c1; e[1] = (bf16_t)c2; e[2] = (bf16_t)c4; e[3] = (bf16_t)c8; }
      else        { e[0] = (bf16_t)s1; e[1] = (bf16_t)s2; e[2] = (bf16_t)s4; e[3] = (bf16_t)s8; }
      *(bf16x4*)(X + sr * XSTR + 64 + d * 8 + (sp & 1) * 4) = e;
    } else if (sp == 6) {
      bf16x8 z = {};
      *(bf16x8*)(X + sr * XSTR + 88) = z;   // pad cols 88..95 (zero k-rows)
    } else {
      float ox = sample_xyz[g * 3 + 0] - map_xyz[idx * 3 + 0];
      float oy = sample_xyz[g * 3 + 1] - map_xyz[idx * 3 + 1];
      float oz = sample_xyz[g * 3 + 2] - map_xyz[idx * 3 + 2];
      wtbuf[sr] = __expf(-10.f * sqrtf(ox * ox + oy * oy + oz * oz));
    }
  };

  // L0: bf16 MFMA (K=96); W0/b0 pre-scaled by S1 -> acc IS the quant value
  auto L0 = [&](const bf16_t* X, char* Qout) {
    f32x4 bi = *(const f32x4*)(sB0 + wid * 16 + q * 4);   // pre-scaled by S1
    f32x4 acc[4] = {bi, bi, bi, bi};
    const bf16_t* rb = X + n * XSTR + q * 8;
    char* wb = Qout + n * QSTR + wid * 16 + q * 4;
    __builtin_amdgcn_s_setprio(1);
#pragma unroll
    for (int st = 0; st < 4; st++)
#pragma unroll
      for (int s = 0; s < 3; s++) {
        bf16x8 b = *(const bf16x8*)(rb + st * 16 * XSTR + s * 32);
        acc[st] = __builtin_amdgcn_mfma_f32_16x16x32_bf16(w0f[s], b, acc[st], 0, 0, 0);
      }
    __builtin_amdgcn_s_setprio(0);
#pragma unroll
    for (int st = 0; st < 4; st++) {
      float r0 = q8pre(acc[st][0]), r1 = q8pre(acc[st][1]);
      float r2 = q8pre(acc[st][2]), r3 = q8pre(acc[st][3]);
      *(unsigned*)(wb + st * 16 * QSTR) = pack4(r0, r1, r2, r3);
    }
  };

  // L1: i8 MFMA K=64, fused dequant+requant (R9-proven scalar path)
  auto L1Q = [&](const char* Qin, char* Qout) {
    i32x4 acc[4] = {};
    const char* rb = Qin + n * QSTR + q * 16;
    char* wb = Qout + n * QSTR + wid * 16 + q * 4;
    f32x4 b1v = *(const f32x4*)(sB1 + wid * 16 + q * 4);   // pre-scaled by S2
    __builtin_amdgcn_s_setprio(1);
#pragma unroll
    for (int st = 0; st < 4; st++)
#pragma unroll
      for (int s = 0; s < 2; s++) {
        i32x4 b = *(const i32x4*)(rb + st * 16 * QSTR + s * 64);
        acc[st] = __builtin_amdgcn_mfma_i32_16x16x64_i8(w1q[s], b, acc[st], 0, 0, 0);
      }
    __builtin_amdgcn_s_setprio(0);
#pragma unroll
    for (int st = 0; st < 4; st++) {
      float r[4];
#pragma unroll
      for (int i = 0; i < 4; i++)
        r[i] = q8pre(fmaf((float)acc[st][i], DQ1S2, b1v[i]));
      *(unsigned*)(wb + st * 16 * QSTR) = pack4(r[0], r[1], r[2], r[3]);
    }
  };

  // L2: i8 MFMA K=64, requant to i8 H3 (mirror of L1Q; S3 folded, b2 pre-scaled)
  auto L2Q = [&](const char* Qin, char* Qout) {
    i32x4 acc[4] = {};
    const char* rb = Qin + n * QSTR + q * 16;
    char* wb = Qout + n * QSTR + wid * 16 + q * 4;
    f32x4 b2v = *(const f32x4*)(sB2 + wid * 16 + q * 4);   // pre-scaled by S3
    __builtin_amdgcn_s_setprio(1);
#pragma unroll
    for (int st = 0; st < 4; st++)
#pragma unroll
      for (int s = 0; s < 2; s++) {
        i32x4 b = *(const i32x4*)(rb + st * 16 * QSTR + s * 64);
        acc[st] = __builtin_amdgcn_mfma_i32_16x16x64_i8(w2q[s], b, acc[st], 0, 0, 0);
      }
    __builtin_amdgcn_s_setprio(0);
#pragma unroll
    for (int st = 0; st < 4; st++) {
      float r[4];
#pragma unroll
      for (int i = 0; i < 4; i++)
        r[i] = q8pre(fmaf((float)acc[st][i], DQ2S3, b2v[i]));
      *(unsigned*)(wb + st * 16 * QSTR) = pack4(r[0], r[1], r[2], r[3]);
    }
  };

  // KRED: i8 H3 in (u16 read = 2 cols), sext + fma; 1/S3 folded into inv
  auto KRED = [&](const char* Qin, const float* wt, const float* ws_, bf16_t* FS) {
    int g = tid >> 6;
    int c = (tid & 63) * 2;
    const char* kb = Qin + g * 8 * QSTR + c;
    float a0 = 0.f, a1 = 0.f;
#pragma unroll
    for (int k = 0; k < 8; k++) {
      float wk = wt[g * 8 + k];
      int us = *(const unsigned short*)(kb + k * QSTR);
      a0 = fmaf(wk, (float)((us << 24) >> 24), a0);   // sext low byte
      a1 = fmaf(wk, (float)((us << 16) >> 24), a1);   // sext high byte
    }
    float inv = 1.f / (ws_[g] * S3_Q);
    bf16x2 fo;
    fo[0] = (bf16_t)(a0 * inv);
    fo[1] = (bf16_t)(a1 * inv);
    *(bf16x2*)(FS + g * HSTR + c) = fo;
  };

  // HEADS: B-cols 8..15 are discarded in D -> zero-filled masked loads (8-row sFS)
  auto HEADS = [&](const bf16_t* FS, bf16_t* AR) {
    f32x4 ha = *(const f32x4*)(sBH + wid * 16 + q * 4);
    const bf16_t* rb = FS + n * HSTR + q * 8;
    bf16x8 bb[4] = {};
    if (n < 8) {
#pragma unroll
      for (int s = 0; s < 4; s++) bb[s] = *(const bf16x8*)(rb + s * 32);
    }
    __builtin_amdgcn_s_setprio(1);
#pragma unroll
    for (int s = 0; s < 4; s++)
      ha = __builtin_amdgcn_mfma_f32_16x16x32_bf16(hdf[s], bb[s], ha, 0, 0, 0);
    __builtin_amdgcn_s_setprio(0);
    if (n < 8) {
      const int base = (wid < 4) ? 64 : 0;    // a-vals high, r-vals low
      bf16x4 o;
      o[0] = (bf16_t)lrelu(ha[0]);
      o[1] = (bf16_t)lrelu(ha[1]);
      o[2] = (bf16_t)lrelu(ha[2]);
      o[3] = (bf16_t)lrelu(ha[3]);
      *(bf16x4*)(AR + n * HSTR + base + (wid & 3) * 16 + q * 4) = o;
    }
  };

  auto FINALS = [&](int tile) {
    if (wid == 0) {
      f32x4 c = *(const f32x4*)sFBv;
      const bf16_t* ab = sFB + l * 8;
      const bf16_t* rb = sAR + n * HSTR + q * 8;
      bf16x8 bb[4] = {};
      if (n < 8) {
#pragma unroll
        for (int s = 0; s < 4; s++) bb[s] = *(const bf16x8*)(rb + s * 32);
      }
#pragma unroll
      for (int s = 0; s < 4; s++) {
        bf16x8 a = *(const bf16x8*)(ab + s * 512);
        c = __builtin_amdgcn_mfma_f32_16x16x32_bf16(a, bb[s], c, 0, 0, 0);
      }
      if (q == 0 && n < 8) {
        float4 o;
        o.x = sigmoidf(c[0]);
        o.y = sigmoidf(c[1]);
        o.z = sigmoidf(c[2]);
        o.w = sigmoidf(c[3]);
        ((float4*)ar_out)[tile * 8 + n] = o;
      }
    }
  };

  // ---- one-time LDS init (no FS/AR zero rows anymore) ----
  {
    int e0 = tid * 4;
    int jb = e0 & 7, ll = (e0 >> 3) & 63, s = e0 >> 9;
    int m = ll & 15;
#pragma unroll
    for (int ii = 0; ii < 4; ii++) {
      int k = s * 32 + (ll >> 4) * 8 + jb + ii;
      float v = 0.f;
      if (k < 64)  { if (m < 3) v = wr1g[k * 3 + m]; }
      else         { if (m == 3) v = wa1g[k - 64]; }
      sFB[e0 + ii] = (bf16_t)v;
    }
  }
  if (tid < 128)      sB0[tid] = b0g[tid] * S1_Q;               // pre-scaled for L0
  else if (tid < 256) sB1[tid - 128] = b1g[tid - 128] * S2_Q;   // pre-scaled for L1Q
  else if (tid < 384) sB2[tid - 256] = b2g[tid - 256] * S3_Q;   // pre-scaled for L2Q
  else { int t = tid - 384; sBH[t] = (t < 64) ? ba0g[t] : br0g[t - 64]; }
  if (tid < 4) sFBv[tid] = (tid < 3) ? br1g[tid] : ba1g[0];
  __syncthreads();

  // ---- dual-stream pipeline, guarded (block-uniform, monotone guards) ----
  for (int it = 0; it <= NITG; ++it) {
    const int tA  = (int)blockIdx.x + (2 * it) * GRID;
    const int tB  = (int)blockIdx.x + (2 * it + 1) * GRID;
    const int tAp = tA - 2 * GRID;
    const int tBp = tB - 2 * GRID;
    const bool aC = (tA < NTILES);             // current A tile valid
    const bool bC = (tB < NTILES);             // current B tile valid
    const bool aP = (it > 0) && (tAp < NTILES);// previous-A pipeline stage valid
    const bool bP = (it > 0) && (tBp < NTILES);// previous-B pipeline stage valid

    // ---- p1: commitA(sX) | L2B(sQ2->sQ3) | finalsA ----
    if (aC) COMMIT(tA, sX, sWtA);
    if (bP) L2Q(sQ2, sQ3);
    if (aP) FINALS(tAp);
    __syncthreads();

    // ---- p2: L0A(sX->sQ1) | kredB(sQ3->sFS) | sWsA ----
    if (aC) L0(sX, sQ1);
    if (bP) KRED(sQ3, sWtB, sWsB, sFS);
    if (aC && tid < 8) {
      float ss = 0.f;
#pragma unroll
      for (int k = 0; k < 8; k++) ss += sWtA[tid * 8 + k];
      sWsA[tid] = ss;
    }
    __syncthreads();

    // ---- p3: L1A(sQ1->sQ2) | headsB(sFS->sAR) ----
    if (aC) L1Q(sQ1, sQ2);
    if (bP) HEADS(sFS, sAR);
    __syncthreads();

    // ---- p4: L2A(sQ2->sQ3) | commitB(sX) | finalsB ----
    if (bC) COMMIT(tB, sX, sWtB);
    if (aC) L2Q(sQ2, sQ3);
    if (bP) FINALS(tBp);
    __syncthreads();

    // ---- p5: kredA(sQ3) | L0B(sX->sQ1) | sWsB ----
    if (bC) L0(sX, sQ1);
    if (aC) KRED(sQ3, sWtA, sWsA, sFS);
    if (bC && tid < 8) {
      float ss = 0.f;
#pragma unroll
      for (int k = 0; k < 8; k++) ss += sWtB[tid * 8 + k];
      sWsB[tid] = ss;
    }
    __syncthreads();

    // ---- p6: headsA(sFS->sAR) | L1B(sQ1->sQ2) ----
    if (aC) HEADS(sFS, sAR);
    if (bC) L1Q(sQ1, sQ2);
    __syncthreads();
  }
}

// ---------------------------------------------------------------------------
// Volume rendering (champion version, separate kernel)
// ---------------------------------------------------------------------------
__global__ __launch_bounds__(512)
void render_kernel(const float* __restrict__ ar, const float* __restrict__ dcam,
                   float* __restrict__ out) {
  int ray = blockIdx.x * 8 + (threadIdx.x >> 6);
  int s = threadIdx.x & 63;
  float4 v = ((const float4*)ar)[ray * 64 + s];
  float alpha = v.w;
  float t = 1.f - alpha + 1e-10f;
  float p = t;
#pragma unroll
  for (int d = 1; d < 64; d <<= 1) {
    float o = __shfl_up(p, d);
    if (s >= d) p *= o;
  }
  float pm1 = __shfl_up(p, 1);
  float T = (s == 0) ? 1.f : pm1;
  float bl = alpha * T;
  float dist = 1.f + 1.25f * dcam[ray * 64 + s];
  float cr = v.x * bl, cg = v.y * bl, cb = v.z * bl, cd = dist * bl, ca = bl;
#pragma unroll
  for (int d = 32; d > 0; d >>= 1) {
    cr += __shfl_xor(cr, d);
    cg += __shfl_xor(cg, d);
    cb += __shfl_xor(cb, d);
    cd += __shfl_xor(cd, d);
    ca += __shfl_xor(ca, d);
  }
  if (s == 0) {
    out[ray * 5 + 0] = cr; out[ray * 5 + 1] = cg; out[ray * 5 + 2] = cb;
    out[ray * 5 + 3] = cd; out[ray * 5 + 4] = ca;
  }
}

// ---------------------------------------------------------------------------
extern "C" void kernel_launch(void* const* d_in, const int* in_sizes, int n_in,
                              void* d_out, int out_size, void* d_ws, size_t ws_size,
                              hipStream_t stream) {
  const float* map_xyz    = (const float*)d_in[0];
  const float* map_feat   = (const float*)d_in[1];
  const int*   ind        = (const int*)d_in[2];
  const float* sample_xyz = (const float*)d_in[3];
  const float* dist_cam   = (const float*)d_in[4];
  const float* W0  = (const float*)d_in[5];
  const float* b0  = (const float*)d_in[6];
  const float* W1  = (const float*)d_in[7];
  const float* b1  = (const float*)d_in[8];
  const float* W2  = (const float*)d_in[9];
  const float* b2  = (const float*)d_in[10];
  const float* Wa0 = (const float*)d_in[11];
  const float* ba0 = (const float*)d_in[12];
  const float* Wa1 = (const float*)d_in[13];
  const float* ba1 = (const float*)d_in[14];
  const float* Wr0 = (const float*)d_in[15];
  const float* br0 = (const float*)d_in[16];
  const float* Wr1 = (const float*)d_in[17];
  const float* br1 = (const float*)d_in[18];

  bf16_t* wpack = (bf16_t*)d_ws;
  char*   wq    = (char*)d_ws + PKQ_OFF;
  float*  ar    = (float*)((char*)d_ws + WS_AR_BYTES);

  pack_weights<<<240, 256, 0, stream>>>(W0, W1, W2, Wa0, Wr0, wpack);
  pack_w12_i8<<<128, 256, 0, stream>>>(W1, W2, wq);
  nerf_main<<<GRID, 512, 0, stream>>>(map_xyz, map_feat, ind, sample_xyz,
                                      b0, b1, b2, ba0, Wa1, ba1, br0, Wr1, br1,
                                      wpack, ar);
  render_kernel<<<256, 512, 0, stream>>>(ar, dist_cam, (float*)d_out);
}

// Round 12
// 388.541 us; speedup vs baseline: 1.1079x; 1.1079x over previous
//
#include <hip/hip_runtime.h>

typedef __bf16 bf16_t;
typedef __bf16 bf16x2 __attribute__((ext_vector_type(2)));
typedef __bf16 bf16x4 __attribute__((ext_vector_type(4)));
typedef __bf16 bf16x8 __attribute__((ext_vector_type(8)));
typedef float  f32x4  __attribute__((ext_vector_type(4)));
typedef int    i32x4  __attribute__((ext_vector_type(4)));

#define NPIX 2048
#define NS   64
#define NK   8
#define NSAMP (NPIX*NS)          // 131072
#define NROWS (NSAMP*NK)         // 1048576
#define TROWS 64
#define NTILES (NROWS/TROWS)     // 16384
#define GRID   768               // 3 blocks/CU via LDS limit (52KB); guarded schedule
#define NITG   11                // ceil(NTILES / (2*GRID)); loop 0..NITG inclusive (drain)
#define XSTR 104                 // 96 cols + 8 pad (bf16), rows 16B-aligned
#define HSTR 136                 // bf16 feat_s/AR rows (8 rows only)
#define QSTR 144                 // i8 H1/H2/H3 rows: 16B-aligned, 36dw ≡ 4 mod 32 (2-way, free)

// packed bf16 weight fragment bases (in bf16x8 units) — unchanged
#define PK_W0 0
#define PK_W1 1536
#define PK_W2 3584
#define PK_WA 5632
#define PK_WR 6656
#define PK_TOT 7680

#define PKQ_OFF   122880         // byte offset of i8 W1/W2 packs in workspace
#define WS_AR_BYTES (122880 + 32768)   // ar after the 2x16KB i8 packs

// ---- quantization scales (S1/S2 validated R8/R9; S3 validated R11) ----
#define SW_Q 300.0f              // W1/W2 weight scale
#define S1_Q 62.0f               // H1 scale (folded into W0/b0)
#define S2_Q 87.0f               // H2 scale
#define S3_Q 76.0f               // H3 scale (range ±1.67, step 0.013)
#define DQ1S2 (S2_Q / (S1_Q * SW_Q))   // L1 acc -> S2 units (lrelu homogeneous)
#define DQ2S3 (S3_Q / (S2_Q * SW_Q))   // L2 acc -> S3 units (b2 pre-scaled by S3)
#define RMAGIC 12582912.f        // 1.5*2^23: +RMAGIC = RNE round, int8 in mantissa low byte

// ---------------------------------------------------------------------------
// bf16 pack (R9 verbatim; W0 pre-scaled by S1_Q)
// ---------------------------------------------------------------------------
__global__ void pack_weights(const float* __restrict__ W0, const float* __restrict__ W1,
                             const float* __restrict__ W2, const float* __restrict__ Wa0,
                             const float* __restrict__ Wr0, bf16_t* __restrict__ dst0) {
  int tid = blockIdx.x * blockDim.x + threadIdx.x;
  if (tid >= PK_TOT * 8) return;
  const float* src; bf16_t* dst; int e, KD, ND, KS; float scl = 1.f;
  if (tid < 12288)      { src = W0;  dst = dst0;         e = tid;         KD = 88;  ND = 128; KS = 3; scl = S1_Q; }
  else if (tid < 28672) { src = W1;  dst = dst0 + 12288; e = tid - 12288; KD = 128; ND = 128; KS = 4; }
  else if (tid < 45056) { src = W2;  dst = dst0 + 28672; e = tid - 28672; KD = 128; ND = 128; KS = 4; }
  else if (tid < 53248) { src = Wa0; dst = dst0 + 45056; e = tid - 45056; KD = 128; ND = 64;  KS = 4; }
  else                  { src = Wr0; dst = dst0 + 53248; e = tid - 53248; KD = 128; ND = 64;  KS = 4; }
  int j = e & 7, l = (e >> 3) & 63, f = e >> 9;
  int s = f % KS, t = f / KS;
  int row = s * 32 + (l >> 4) * 8 + j;
  int col = t * 16 + (l & 15);
  float v = (row < KD) ? src[row * ND + col] * scl : 0.f;
  dst[e] = (bf16_t)v;
}

// ---------------------------------------------------------------------------
// i8 pack for W1/W2 (R9 verbatim)
// ---------------------------------------------------------------------------
__global__ void pack_w12_i8(const float* __restrict__ W1, const float* __restrict__ W2,
                            char* __restrict__ dstq) {
  int tid = blockIdx.x * blockDim.x + threadIdx.x;
  if (tid >= 2 * 16384) return;
  const float* src = (tid < 16384) ? W1 : W2;
  int e = tid & 16383;
  int j = e & 15, l = (e >> 4) & 63, f = e >> 10;
  int s = f & 1, t = f >> 1;
  int k = s * 64 + ((l >> 4) << 4) + j;
  int c = t * 16 + (l & 15);
  int iv = (int)rintf(src[k * 128 + c] * SW_Q);
  iv = iv > 127 ? 127 : (iv < -127 ? -127 : iv);
  dstq[tid] = (char)iv;
}

__device__ __forceinline__ float lrelu(float v) { return fmaxf(v, 0.1f * v); }
__device__ __forceinline__ float sigmoidf(float x) { return 1.f / (1.f + __expf(-x)); }

// R9-proven scalar quant helpers
__device__ __forceinline__ float q8pre(float v) {
  float h = fmaxf(v, 0.1f * v);
  h = fminf(fmaxf(h, -127.f), 127.f);
  return h + RMAGIC;
}
__device__ __forceinline__ unsigned pack4(float r0, float r1, float r2, float r3) {
  unsigned t0 = __builtin_amdgcn_perm(__builtin_bit_cast(unsigned, r1),
                                      __builtin_bit_cast(unsigned, r0), 0x00000400u);
  unsigned t1 = __builtin_amdgcn_perm(__builtin_bit_cast(unsigned, r3),
                                      __builtin_bit_cast(unsigned, r2), 0x00000400u);
  return __builtin_amdgcn_perm(t1, t0, 0x05040100u);
}

// ---------------------------------------------------------------------------
// Round-18 (R12): R11's LDS diet WITHOUT the launch-bound squeeze.
// R11 post-mortem: launch_bounds(512,6) forced VGPR to 40 -> the ~44 regs of
// persistent weight frags spilled to scratch -> FETCH 187->608MB, WRITE
// 2->50MB, dur 197->269 despite occupancy 42->67%. The LDS diet itself worked
// (52.2KB, 3 blocks resident, correctness clean). Fix: launch_bounds back to
// (512,4) — at ~60 VGPRs the RF admits 8 waves/SIMD, so HW occupancy becomes
// LDS-limited at 3 blocks/CU = 24 waves, no allocator starvation.
// Everything else byte-identical to R11 (i8 H3, 8-row sFS/sAR, guarded
// GRID=768 dual-stream schedule).
// ---------------------------------------------------------------------------
__global__ __launch_bounds__(512, 4)
void nerf_main(const float* __restrict__ map_xyz, const float* __restrict__ map_feat,
               const int* __restrict__ ind, const float* __restrict__ sample_xyz,
               const float* __restrict__ b0g, const float* __restrict__ b1g,
               const float* __restrict__ b2g, const float* __restrict__ ba0g,
               const float* __restrict__ wa1g, const float* __restrict__ ba1g,
               const float* __restrict__ br0g, const float* __restrict__ wr1g,
               const float* __restrict__ br1g, const bf16_t* __restrict__ wpack,
               float* __restrict__ ar_out)
{
  __shared__ __align__(16) bf16_t sX[TROWS * XSTR];     // X (bf16)            13312 B
  __shared__ __align__(16) char   sQ1[TROWS * QSTR];    // H1 (i8)              9216 B
  __shared__ __align__(16) char   sQ2[TROWS * QSTR];    // H2 (i8)              9216 B
  __shared__ __align__(16) char   sQ3[TROWS * QSTR];    // H3 (i8)              9216 B
  __shared__ __align__(16) bf16_t sFS[8 * HSTR];        // feat_s, 8 rows       2176 B
  __shared__ __align__(16) bf16_t sAR[8 * HSTR];        // [r|a], 8 rows        2176 B
  __shared__ __align__(16) bf16_t sFB[2048];            // finals A-frags       4096 B
  __shared__ __align__(16) float sWtA[TROWS], sWtB[TROWS];
  __shared__ float sWsA[8], sWsB[8];
  __shared__ __align__(16) float sB0[128], sB1[128], sB2[128], sBH[128], sFBv[4];

  const int tid = threadIdx.x;
  const int wid = tid >> 6, l = tid & 63;
  const int q = l >> 4, n = l & 15;
  const int sr = tid >> 3, sp = tid & 7;   // staging thread coords

  // ---- persistent weights: W0/heads bf16 A-frags, W1/W2 i8 A-frags ----
  const bf16x8* pk = (const bf16x8*)wpack;
  bf16x8 w0f[3], hdf[4];
#pragma unroll
  for (int s = 0; s < 3; s++) w0f[s] = pk[PK_W0 + (wid * 3 + s) * 64 + l];
#pragma unroll
  for (int s = 0; s < 4; s++)
    hdf[s] = pk[(wid < 4 ? PK_WA : PK_WR) + ((wid & 3) * 4 + s) * 64 + l];
  const i32x4* pq = (const i32x4*)((const char*)wpack + PKQ_OFF);
  i32x4 w1q[2], w2q[2];
#pragma unroll
  for (int s = 0; s < 2; s++) {
    w1q[s] = pq[(wid * 2 + s) * 64 + l];
    w2q[s] = pq[1024 + (wid * 2 + s) * 64 + l];
  }

  // ---- phase ops ----
  auto COMMIT = [&](int tile, bf16_t* X, float* wtbuf) {
    const int m = tile * TROWS + sr;
    const int idx = ind[m];
    const float4* fp = (const float4*)(map_feat + (size_t)idx * 64 + sp * 8);
    float4 f0 = fp[0], f1 = fp[1];
    bf16x8 v;
    v[0] = (bf16_t)f0.x; v[1] = (bf16_t)f0.y; v[2] = (bf16_t)f0.z; v[3] = (bf16_t)f0.w;
    v[4] = (bf16_t)f1.x; v[5] = (bf16_t)f1.y; v[6] = (bf16_t)f1.z; v[7] = (bf16_t)f1.w;
    *(bf16x8*)(X + sr * XSTR + sp * 8) = v;
    const int g = m >> 3;
    if (sp < 6) {
      const int d = sp >> 1;
      float o = sample_xyz[g * 3 + d] - map_xyz[idx * 3 + d];
      float s1 = __sinf(o), c1 = __cosf(o);
      float s2 = 2.f * s1 * c1, c2 = 1.f - 2.f * s1 * s1;
      float s4 = 2.f * s2 * c2, c4 = 1.f - 2.f * s2 * s2;
      float s8 = 2.f * s4 * c4, c8 = 1.f - 2.f * s4 * s4;
      bf16x4 e;
      if (sp & 1) { e[0] = (bf16_t)c1; e[1] = (bf16_t)c2; e[2] = (bf16_t)c4; e[3] = (bf16_t)c8; }
      else        { e[0] = (bf16_t)s1; e[1] = (bf16_t)s2; e[2] = (bf16_t)s4; e[3] = (bf16_t)s8; }
      *(bf16x4*)(X + sr * XSTR + 64 + d * 8 + (sp & 1) * 4) = e;
    } else if (sp == 6) {
      bf16x8 z = {};
      *(bf16x8*)(X + sr * XSTR + 88) = z;   // pad cols 88..95 (zero k-rows)
    } else {
      float ox = sample_xyz[g * 3 + 0] - map_xyz[idx * 3 + 0];
      float oy = sample_xyz[g * 3 + 1] - map_xyz[idx * 3 + 1];
      float oz = sample_xyz[g * 3 + 2] - map_xyz[idx * 3 + 2];
      wtbuf[sr] = __expf(-10.f * sqrtf(ox * ox + oy * oy + oz * oz));
    }
  };

  // L0: bf16 MFMA (K=96); W0/b0 pre-scaled by S1 -> acc IS the quant value
  auto L0 = [&](const bf16_t* X, char* Qout) {
    f32x4 bi = *(const f32x4*)(sB0 + wid * 16 + q * 4);   // pre-scaled by S1
    f32x4 acc[4] = {bi, bi, bi, bi};
    const bf16_t* rb = X + n * XSTR + q * 8;
    char* wb = Qout + n * QSTR + wid * 16 + q * 4;
    __builtin_amdgcn_s_setprio(1);
#pragma unroll
    for (int st = 0; st < 4; st++)
#pragma unroll
      for (int s = 0; s < 3; s++) {
        bf16x8 b = *(const bf16x8*)(rb + st * 16 * XSTR + s * 32);
        acc[st] = __builtin_amdgcn_mfma_f32_16x16x32_bf16(w0f[s], b, acc[st], 0, 0, 0);
      }
    __builtin_amdgcn_s_setprio(0);
#pragma unroll
    for (int st = 0; st < 4; st++) {
      float r0 = q8pre(acc[st][0]), r1 = q8pre(acc[st][1]);
      float r2 = q8pre(acc[st][2]), r3 = q8pre(acc[st][3]);
      *(unsigned*)(wb + st * 16 * QSTR) = pack4(r0, r1, r2, r3);
    }
  };

  // L1: i8 MFMA K=64, fused dequant+requant (R9-proven scalar path)
  auto L1Q = [&](const char* Qin, char* Qout) {
    i32x4 acc[4] = {};
    const char* rb = Qin + n * QSTR + q * 16;
    char* wb = Qout + n * QSTR + wid * 16 + q * 4;
    f32x4 b1v = *(const f32x4*)(sB1 + wid * 16 + q * 4);   // pre-scaled by S2
    __builtin_amdgcn_s_setprio(1);
#pragma unroll
    for (int st = 0; st < 4; st++)
#pragma unroll
      for (int s = 0; s < 2; s++) {
        i32x4 b = *(const i32x4*)(rb + st * 16 * QSTR + s * 64);
        acc[st] = __builtin_amdgcn_mfma_i32_16x16x64_i8(w1q[s], b, acc[st], 0, 0, 0);
      }
    __builtin_amdgcn_s_setprio(0);
#pragma unroll
    for (int st = 0; st < 4; st++) {
      float r[4];
#pragma unroll
      for (int i = 0; i < 4; i++)
        r[i] = q8pre(fmaf((float)acc[st][i], DQ1S2, b1v[i]));
      *(unsigned*)(wb + st * 16 * QSTR) = pack4(r[0], r[1], r[2], r[3]);
    }
  };

  // L2: i8 MFMA K=64, requant to i8 H3 (mirror of L1Q; S3 folded, b2 pre-scaled)
  auto L2Q = [&](const char* Qin, char* Qout) {
    i32x4 acc[4] = {};
    const char* rb = Qin + n * QSTR + q * 16;
    char* wb = Qout + n * QSTR + wid * 16 + q * 4;
    f32x4 b2v = *(const f32x4*)(sB2 + wid * 16 + q * 4);   // pre-scaled by S3
    __builtin_amdgcn_s_setprio(1);
#pragma unroll
    for (int st = 0; st < 4; st++)
#pragma unroll
      for (int s = 0; s < 2; s++) {
        i32x4 b = *(const i32x4*)(rb + st * 16 * QSTR + s * 64);
        acc[st] = __builtin_amdgcn_mfma_i32_16x16x64_i8(w2q[s], b, acc[st], 0, 0, 0);
      }
    __builtin_amdgcn_s_setprio(0);
#pragma unroll
    for (int st = 0; st < 4; st++) {
      float r[4];
#pragma unroll
      for (int i = 0; i < 4; i++)
        r[i] = q8pre(fmaf((float)acc[st][i], DQ2S3, b2v[i]));
      *(unsigned*)(wb + st * 16 * QSTR) = pack4(r[0], r[1], r[2], r[3]);
    }
  };

  // KRED: i8 H3 in (u16 read = 2 cols), sext + fma; 1/S3 folded into inv
  auto KRED = [&](const char* Qin, const float* wt, const float* ws_, bf16_t* FS) {
    int g = tid >> 6;
    int c = (tid & 63) * 2;
    const char* kb = Qin + g * 8 * QSTR + c;
    float a0 = 0.f, a1 = 0.f;
#pragma unroll
    for (int k = 0; k < 8; k++) {
      float wk = wt[g * 8 + k];
      int us = *(const unsigned short*)(kb + k * QSTR);
      a0 = fmaf(wk, (float)((us << 24) >> 24), a0);   // sext low byte
      a1 = fmaf(wk, (float)((us << 16) >> 24), a1);   // sext high byte
    }
    float inv = 1.f / (ws_[g] * S3_Q);
    bf16x2 fo;
    fo[0] = (bf16_t)(a0 * inv);
    fo[1] = (bf16_t)(a1 * inv);
    *(bf16x2*)(FS + g * HSTR + c) = fo;
  };

  // HEADS: B-cols 8..15 are discarded in D -> zero-filled masked loads (8-row sFS)
  auto HEADS = [&](const bf16_t* FS, bf16_t* AR) {
    f32x4 ha = *(const f32x4*)(sBH + wid * 16 + q * 4);
    const bf16_t* rb = FS + n * HSTR + q * 8;
    bf16x8 bb[4] = {};
    if (n < 8) {
#pragma unroll
      for (int s = 0; s < 4; s++) bb[s] = *(const bf16x8*)(rb + s * 32);
    }
    __builtin_amdgcn_s_setprio(1);
#pragma unroll
    for (int s = 0; s < 4; s++)
      ha = __builtin_amdgcn_mfma_f32_16x16x32_bf16(hdf[s], bb[s], ha, 0, 0, 0);
    __builtin_amdgcn_s_setprio(0);
    if (n < 8) {
      const int base = (wid < 4) ? 64 : 0;    // a-vals high, r-vals low
      bf16x4 o;
      o[0] = (bf16_t)lrelu(ha[0]);
      o[1] = (bf16_t)lrelu(ha[1]);
      o[2] = (bf16_t)lrelu(ha[2]);
      o[3] = (bf16_t)lrelu(ha[3]);
      *(bf16x4*)(AR + n * HSTR + base + (wid & 3) * 16 + q * 4) = o;
    }
  };

  auto FINALS = [&](int tile) {
    if (wid == 0) {
      f32x4 c = *(const f32x4*)sFBv;
      const bf16_t* ab = sFB + l * 8;
      const bf16_t* rb = sAR + n * HSTR + q * 8;
      bf16x8 bb[4] = {};
      if (n < 8) {
#pragma unroll
        for (int s = 0; s < 4; s++) bb[s] = *(const bf16x8*)(rb + s * 32);
      }
#pragma unroll
      for (int s = 0; s < 4; s++) {
        bf16x8 a = *(const bf16x8*)(ab + s * 512);
        c = __builtin_amdgcn_mfma_f32_16x16x32_bf16(a, bb[s], c, 0, 0, 0);
      }
      if (q == 0 && n < 8) {
        float4 o;
        o.x = sigmoidf(c[0]);
        o.y = sigmoidf(c[1]);
        o.z = sigmoidf(c[2]);
        o.w = sigmoidf(c[3]);
        ((float4*)ar_out)[tile * 8 + n] = o;
      }
    }
  };

  // ---- one-time LDS init ----
  {
    int e0 = tid * 4;
    int jb = e0 & 7, ll = (e0 >> 3) & 63, s = e0 >> 9;
    int m = ll & 15;
#pragma unroll
    for (int ii = 0; ii < 4; ii++) {
      int k = s * 32 + (ll >> 4) * 8 + jb + ii;
      float v = 0.f;
      if (k < 64)  { if (m < 3) v = wr1g[k * 3 + m]; }
      else         { if (m == 3) v = wa1g[k - 64]; }
      sFB[e0 + ii] = (bf16_t)v;
    }
  }
  if (tid < 128)      sB0[tid] = b0g[tid] * S1_Q;               // pre-scaled for L0
  else if (tid < 256) sB1[tid - 128] = b1g[tid - 128] * S2_Q;   // pre-scaled for L1Q
  else if (tid < 384) sB2[tid - 256] = b2g[tid - 256] * S3_Q;   // pre-scaled for L2Q
  else { int t = tid - 384; sBH[t] = (t < 64) ? ba0g[t] : br0g[t - 64]; }
  if (tid < 4) sFBv[tid] = (tid < 3) ? br1g[tid] : ba1g[0];
  __syncthreads();

  // ---- dual-stream pipeline, guarded (block-uniform, monotone guards) ----
  for (int it = 0; it <= NITG; ++it) {
    const int tA  = (int)blockIdx.x + (2 * it) * GRID;
    const int tB  = (int)blockIdx.x + (2 * it + 1) * GRID;
    const int tAp = tA - 2 * GRID;
    const int tBp = tB - 2 * GRID;
    const bool aC = (tA < NTILES);             // current A tile valid
    const bool bC = (tB < NTILES);             // current B tile valid
    const bool aP = (it > 0) && (tAp < NTILES);// previous-A pipeline stage valid
    const bool bP = (it > 0) && (tBp < NTILES);// previous-B pipeline stage valid

    // ---- p1: commitA(sX) | L2B(sQ2->sQ3) | finalsA ----
    if (aC) COMMIT(tA, sX, sWtA);
    if (bP) L2Q(sQ2, sQ3);
    if (aP) FINALS(tAp);
    __syncthreads();

    // ---- p2: L0A(sX->sQ1) | kredB(sQ3->sFS) | sWsA ----
    if (aC) L0(sX, sQ1);
    if (bP) KRED(sQ3, sWtB, sWsB, sFS);
    if (aC && tid < 8) {
      float ss = 0.f;
#pragma unroll
      for (int k = 0; k < 8; k++) ss += sWtA[tid * 8 + k];
      sWsA[tid] = ss;
    }
    __syncthreads();

    // ---- p3: L1A(sQ1->sQ2) | headsB(sFS->sAR) ----
    if (aC) L1Q(sQ1, sQ2);
    if (bP) HEADS(sFS, sAR);
    __syncthreads();

    // ---- p4: L2A(sQ2->sQ3) | commitB(sX) | finalsB ----
    if (bC) COMMIT(tB, sX, sWtB);
    if (aC) L2Q(sQ2, sQ3);
    if (bP) FINALS(tBp);
    __syncthreads();

    // ---- p5: kredA(sQ3) | L0B(sX->sQ1) | sWsB ----
    if (bC) L0(sX, sQ1);
    if (aC) KRED(sQ3, sWtA, sWsA, sFS);
    if (bC && tid < 8) {
      float ss = 0.f;
#pragma unroll
      for (int k = 0; k < 8; k++) ss += sWtB[tid * 8 + k];
      sWsB[tid] = ss;
    }
    __syncthreads();

    // ---- p6: headsA(sFS->sAR) | L1B(sQ1->sQ2) ----
    if (aC) HEADS(sFS, sAR);
    if (bC) L1Q(sQ1, sQ2);
    __syncthreads();
  }
}

// ---------------------------------------------------------------------------
// Volume rendering (champion version, separate kernel)
// ---------------------------------------------------------------------------
__global__ __launch_bounds__(512)
void render_kernel(const float* __restrict__ ar, const float* __restrict__ dcam,
                   float* __restrict__ out) {
  int ray = blockIdx.x * 8 + (threadIdx.x >> 6);
  int s = threadIdx.x & 63;
  float4 v = ((const float4*)ar)[ray * 64 + s];
  float alpha = v.w;
  float t = 1.f - alpha + 1e-10f;
  float p = t;
#pragma unroll
  for (int d = 1; d < 64; d <<= 1) {
    float o = __shfl_up(p, d);
    if (s >= d) p *= o;
  }
  float pm1 = __shfl_up(p, 1);
  float T = (s == 0) ? 1.f : pm1;
  float bl = alpha * T;
  float dist = 1.f + 1.25f * dcam[ray * 64 + s];
  float cr = v.x * bl, cg = v.y * bl, cb = v.z * bl, cd = dist * bl, ca = bl;
#pragma unroll
  for (int d = 32; d > 0; d >>= 1) {
    cr += __shfl_xor(cr, d);
    cg += __shfl_xor(cg, d);
    cb += __shfl_xor(cb, d);
    cd += __shfl_xor(cd, d);
    ca += __shfl_xor(ca, d);
  }
  if (s == 0) {
    out[ray * 5 + 0] = cr; out[ray * 5 + 1] = cg; out[ray * 5 + 2] = cb;
    out[ray * 5 + 3] = cd; out[ray * 5 + 4] = ca;
  }
}

// ---------------------------------------------------------------------------
extern "C" void kernel_launch(void* const* d_in, const int* in_sizes, int n_in,
                              void* d_out, int out_size, void* d_ws, size_t ws_size,
                              hipStream_t stream) {
  const float* map_xyz    = (const float*)d_in[0];
  const float* map_feat   = (const float*)d_in[1];
  const int*   ind        = (const int*)d_in[2];
  const float* sample_xyz = (const float*)d_in[3];
  const float* dist_cam   = (const float*)d_in[4];
  const float* W0  = (const float*)d_in[5];
  const float* b0  = (const float*)d_in[6];
  const float* W1  = (const float*)d_in[7];
  const float* b1  = (const float*)d_in[8];
  const float* W2  = (const float*)d_in[9];
  const float* b2  = (const float*)d_in[10];
  const float* Wa0 = (const float*)d_in[11];
  const float* ba0 = (const float*)d_in[12];
  const float* Wa1 = (const float*)d_in[13];
  const float* ba1 = (const float*)d_in[14];
  const float* Wr0 = (const float*)d_in[15];
  const float* br0 = (const float*)d_in[16];
  const float* Wr1 = (const float*)d_in[17];
  const float* br1 = (const float*)d_in[18];

  bf16_t* wpack = (bf16_t*)d_ws;
  char*   wq    = (char*)d_ws + PKQ_OFF;
  float*  ar    = (float*)((char*)d_ws + WS_AR_BYTES);

  pack_weights<<<240, 256, 0, stream>>>(W0, W1, W2, Wa0, Wr0, wpack);
  pack_w12_i8<<<128, 256, 0, stream>>>(W1, W2, wq);
  nerf_main<<<GRID, 512, 0, stream>>>(map_xyz, map_feat, ind, sample_xyz,
                                      b0, b1, b2, ba0, Wa1, ba1, br0, Wr1, br1,
                                      wpack, ar);
  render_kernel<<<256, 512, 0, stream>>>(ar, dist_cam, (float*)d_out);
}

// Round 13
// 360.910 us; speedup vs baseline: 1.1927x; 1.0766x over previous
//
#include <hip/hip_runtime.h>

typedef __bf16 bf16_t;
typedef __bf16 bf16x2 __attribute__((ext_vector_type(2)));
typedef __bf16 bf16x4 __attribute__((ext_vector_type(4)));
typedef __bf16 bf16x8 __attribute__((ext_vector_type(8)));
typedef float  f32x4  __attribute__((ext_vector_type(4)));
typedef int    i32x4  __attribute__((ext_vector_type(4)));

#define NPIX 2048
#define NS   64
#define NK   8
#define NSAMP (NPIX*NS)          // 131072
#define NROWS (NSAMP*NK)         // 1048576
#define TROWS 64
#define NTILES (NROWS/TROWS)     // 16384
#define GRID   512
#define NIT    16                // 32 tiles/block = 16 A + 16 B (strided, champion)
#define XSTR 104                 // 96 cols + 8 pad (bf16), rows 16B-aligned
#define HSTR 136                 // bf16 H3 buffer (champion value)
#define QSTR 144                 // i8 H1/H2 rows: 16B-aligned, 36dw ≡ 4 mod 32 (2-way, free)

// packed bf16 weight fragment bases (in bf16x8 units) — unchanged
#define PK_W0 0
#define PK_W1 1536
#define PK_W2 3584
#define PK_WA 5632
#define PK_WR 6656
#define PK_TOT 7680

#define PKQ_OFF   122880         // byte offset of i8 W1/W2 packs in workspace
#define WS_AR_BYTES (122880 + 32768)   // ar after the 2x16KB i8 packs

// ---- i8 quantization scales (validated R8/R9: absmax at bf16 noise floor) ----
#define SW_Q 300.0f              // W1/W2 weight scale
#define S1_Q 62.0f               // H1 activation scale (folded into W0/b0)
#define S2_Q 87.0f               // H2 activation scale
#define DQ1S2 (S2_Q / (S1_Q * SW_Q))   // L1 acc -> S2 units (lrelu homogeneous)
#define DQ2   (1.0f / (S2_Q * SW_Q))   // L2 acc -> f32
#define RMAGIC 12582912.f        // 1.5*2^23: +RMAGIC = RNE round, int8 in mantissa low byte

// ---------------------------------------------------------------------------
// bf16 pack; W0 section pre-scaled by S1_Q (lrelu homogeneity) so the L0
// epilogue's *S1 multiply disappears; b0 likewise scaled at LDS init.
// ---------------------------------------------------------------------------
__global__ void pack_weights(const float* __restrict__ W0, const float* __restrict__ W1,
                             const float* __restrict__ W2, const float* __restrict__ Wa0,
                             const float* __restrict__ Wr0, bf16_t* __restrict__ dst0) {
  int tid = blockIdx.x * blockDim.x + threadIdx.x;
  if (tid >= PK_TOT * 8) return;
  const float* src; bf16_t* dst; int e, KD, ND, KS; float scl = 1.f;
  if (tid < 12288)      { src = W0;  dst = dst0;         e = tid;         KD = 88;  ND = 128; KS = 3; scl = S1_Q; }
  else if (tid < 28672) { src = W1;  dst = dst0 + 12288; e = tid - 12288; KD = 128; ND = 128; KS = 4; }
  else if (tid < 45056) { src = W2;  dst = dst0 + 28672; e = tid - 28672; KD = 128; ND = 128; KS = 4; }
  else if (tid < 53248) { src = Wa0; dst = dst0 + 45056; e = tid - 45056; KD = 128; ND = 64;  KS = 4; }
  else                  { src = Wr0; dst = dst0 + 53248; e = tid - 53248; KD = 128; ND = 64;  KS = 4; }
  int j = e & 7, l = (e >> 3) & 63, f = e >> 9;
  int s = f % KS, t = f / KS;
  int row = s * 32 + (l >> 4) * 8 + j;
  int col = t * 16 + (l & 15);
  float v = (row < KD) ? src[row * ND + col] * scl : 0.f;
  dst[e] = (bf16_t)v;
}

// ---------------------------------------------------------------------------
// i8 pack for W1/W2: A-fragment of W^T for mfma_i32_16x16x64_i8.
// Layout-agnostic by A/B symmetry: activations use the identical linear
// 16-byte k-chunk per lane-group, so internal k-permutations cancel.
// ---------------------------------------------------------------------------
__global__ void pack_w12_i8(const float* __restrict__ W1, const float* __restrict__ W2,
                            char* __restrict__ dstq) {
  int tid = blockIdx.x * blockDim.x + threadIdx.x;
  if (tid >= 2 * 16384) return;
  const float* src = (tid < 16384) ? W1 : W2;
  int e = tid & 16383;
  int j = e & 15, l = (e >> 4) & 63, f = e >> 10;
  int s = f & 1, t = f >> 1;
  int k = s * 64 + ((l >> 4) << 4) + j;
  int c = t * 16 + (l & 15);
  int iv = (int)rintf(src[k * 128 + c] * SW_Q);
  iv = iv > 127 ? 127 : (iv < -127 ? -127 : iv);
  dstq[tid] = (char)iv;
}

__device__ __forceinline__ float lrelu(float v) { return fmaxf(v, 0.1f * v); }
__device__ __forceinline__ float sigmoidf(float x) { return 1.f / (1.f + __expf(-x)); }

// lrelu -> clamp -> RNE-round-to-int8-in-low-byte (magic). One add replaces
// rndne+cvt; perm replaces and/shl/or. (R9-proven scalar path; R10's packed
// rewrite failed numerically and was abandoned.)
__device__ __forceinline__ float q8pre(float v) {
  float h = fmaxf(v, 0.1f * v);
  h = fminf(fmaxf(h, -127.f), 127.f);
  return h + RMAGIC;
}
__device__ __forceinline__ unsigned pack4(float r0, float r1, float r2, float r3) {
  unsigned t0 = __builtin_amdgcn_perm(__builtin_bit_cast(unsigned, r1),
                                      __builtin_bit_cast(unsigned, r0), 0x00000400u);
  unsigned t1 = __builtin_amdgcn_perm(__builtin_bit_cast(unsigned, r3),
                                      __builtin_bit_cast(unsigned, r2), 0x00000400u);
  return __builtin_amdgcn_perm(t1, t0, 0x05040100u);
}

// ---------------------------------------------------------------------------
// CHAMPION (R9, 357.9us total / 197.6us nerf_main, absmax 0.5): restored
// verbatim after R10-R12 refuted the remaining levers.
// Structure: R4 dual-stream 6-phase schedule; i8 K=64 MFMA for L1/L2 (R8,
// -21% LDS-instr); epilogue VALU diet (R9: S1-folded W0/b0, magic-RNE round,
// v_perm byte pack). Ledger of refuted directions:
//  * packed-f32 VOP3P epilogues (R10): absmax 3.0 — lowering not IEEE-stable.
//  * occupancy 3 blocks/CU (R11/R12): unified RF (60 arch + ~64 acc ~ 124)
//    hard-caps 4 waves/SIMD = 2 blocks/CU; launch_bounds(512,6) spills
//    weights (FETCH 187->608MB); GRID=768 at 2-resident = 1.5 block-rounds.
//  * gather prefetch (R3 ~0), phase diversity alone (R4 ~0), conflict
//    elimination (R5: +16% — LDS time tracks instr count), 32-col waves
//    (R6: VGPR-capped), render fusion (R7: inter-kernel gap is harness-fixed).
// Steady state: VALU 52% + LDS ~50% concurrently busy — balanced dual-pipe
// floor; no remaining single-stream cut moves the wall.
// ---------------------------------------------------------------------------
__global__ __launch_bounds__(512, 4)
void nerf_main(const float* __restrict__ map_xyz, const float* __restrict__ map_feat,
               const int* __restrict__ ind, const float* __restrict__ sample_xyz,
               const float* __restrict__ b0g, const float* __restrict__ b1g,
               const float* __restrict__ b2g, const float* __restrict__ ba0g,
               const float* __restrict__ wa1g, const float* __restrict__ ba1g,
               const float* __restrict__ br0g, const float* __restrict__ wr1g,
               const float* __restrict__ br1g, const bf16_t* __restrict__ wpack,
               float* __restrict__ ar_out)
{
  __shared__ __align__(16) bf16_t sX[TROWS * XSTR];     // X (bf16)
  __shared__ __align__(16) char   sQ1[TROWS * QSTR];    // H1 (i8)
  __shared__ __align__(16) char   sQ2[TROWS * QSTR];    // H2 (i8)
  __shared__ __align__(16) bf16_t sH3[TROWS * HSTR];    // H3 (bf16, for KRED)
  __shared__ __align__(16) bf16_t sFS[16 * HSTR];       // feat_s (rows 8..15 zero)
  __shared__ __align__(16) bf16_t sAR[16 * HSTR];       // [r|a] (rows 8..15 zero)
  __shared__ __align__(16) bf16_t sFB[2048];            // finals A-frags
  __shared__ __align__(16) float sWtA[TROWS], sWtB[TROWS];
  __shared__ float sWsA[8], sWsB[8];
  __shared__ __align__(16) float sB0[128], sB1[128], sB2[128], sBH[128], sFBv[4];

  const int tid = threadIdx.x;
  const int wid = tid >> 6, l = tid & 63;
  const int q = l >> 4, n = l & 15;
  const int sr = tid >> 3, sp = tid & 7;   // staging thread coords

  // ---- persistent weights: W0/heads bf16 A-frags, W1/W2 i8 A-frags ----
  const bf16x8* pk = (const bf16x8*)wpack;
  bf16x8 w0f[3], hdf[4];
#pragma unroll
  for (int s = 0; s < 3; s++) w0f[s] = pk[PK_W0 + (wid * 3 + s) * 64 + l];
#pragma unroll
  for (int s = 0; s < 4; s++)
    hdf[s] = pk[(wid < 4 ? PK_WA : PK_WR) + ((wid & 3) * 4 + s) * 64 + l];
  const i32x4* pq = (const i32x4*)((const char*)wpack + PKQ_OFF);
  i32x4 w1q[2], w2q[2];
#pragma unroll
  for (int s = 0; s < 2; s++) {
    w1q[s] = pq[(wid * 2 + s) * 64 + l];
    w2q[s] = pq[1024 + (wid * 2 + s) * 64 + l];
  }

  // ---- phase ops ----
  auto COMMIT = [&](int tile, bf16_t* X, float* wtbuf) {
    const int m = tile * TROWS + sr;
    const int idx = ind[m];
    const float4* fp = (const float4*)(map_feat + (size_t)idx * 64 + sp * 8);
    float4 f0 = fp[0], f1 = fp[1];
    bf16x8 v;
    v[0] = (bf16_t)f0.x; v[1] = (bf16_t)f0.y; v[2] = (bf16_t)f0.z; v[3] = (bf16_t)f0.w;
    v[4] = (bf16_t)f1.x; v[5] = (bf16_t)f1.y; v[6] = (bf16_t)f1.z; v[7] = (bf16_t)f1.w;
    *(bf16x8*)(X + sr * XSTR + sp * 8) = v;
    const int g = m >> 3;
    if (sp < 6) {
      const int d = sp >> 1;
      float o = sample_xyz[g * 3 + d] - map_xyz[idx * 3 + d];
      float s1 = __sinf(o), c1 = __cosf(o);
      float s2 = 2.f * s1 * c1, c2 = 1.f - 2.f * s1 * s1;
      float s4 = 2.f * s2 * c2, c4 = 1.f - 2.f * s2 * s2;
      float s8 = 2.f * s4 * c4, c8 = 1.f - 2.f * s4 * s4;
      bf16x4 e;
      if (sp & 1) { e[0] = (bf16_t)c1; e[1] = (bf16_t)c2; e[2] = (bf16_t)c4; e[3] = (bf16_t)c8; }
      else        { e[0] = (bf16_t)s1; e[1] = (bf16_t)s2; e[2] = (bf16_t)s4; e[3] = (bf16_t)s8; }
      *(bf16x4*)(X + sr * XSTR + 64 + d * 8 + (sp & 1) * 4) = e;
    } else if (sp == 6) {
      bf16x8 z = {};
      *(bf16x8*)(X + sr * XSTR + 88) = z;   // pad cols 88..95 (zero k-rows)
    } else {
      float ox = sample_xyz[g * 3 + 0] - map_xyz[idx * 3 + 0];
      float oy = sample_xyz[g * 3 + 1] - map_xyz[idx * 3 + 1];
      float oz = sample_xyz[g * 3 + 2] - map_xyz[idx * 3 + 2];
      wtbuf[sr] = __expf(-10.f * sqrtf(ox * ox + oy * oy + oz * oz));
    }
  };

  // L0: bf16 MFMA (K=96); W0/b0 pre-scaled by S1 -> acc IS the quant value
  auto L0 = [&](const bf16_t* X, char* Qout) {
    f32x4 bi = *(const f32x4*)(sB0 + wid * 16 + q * 4);   // pre-scaled by S1
    f32x4 acc[4] = {bi, bi, bi, bi};
    const bf16_t* rb = X + n * XSTR + q * 8;
    char* wb = Qout + n * QSTR + wid * 16 + q * 4;
    __builtin_amdgcn_s_setprio(1);
#pragma unroll
    for (int st = 0; st < 4; st++)
#pragma unroll
      for (int s = 0; s < 3; s++) {
        bf16x8 b = *(const bf16x8*)(rb + st * 16 * XSTR + s * 32);
        acc[st] = __builtin_amdgcn_mfma_f32_16x16x32_bf16(w0f[s], b, acc[st], 0, 0, 0);
      }
    __builtin_amdgcn_s_setprio(0);
#pragma unroll
    for (int st = 0; st < 4; st++) {
      float r0 = q8pre(acc[st][0]), r1 = q8pre(acc[st][1]);
      float r2 = q8pre(acc[st][2]), r3 = q8pre(acc[st][3]);
      *(unsigned*)(wb + st * 16 * QSTR) = pack4(r0, r1, r2, r3);
    }
  };

  // L1: i8 MFMA K=64, fused dequant+requant (magic-round + perm pack)
  auto L1Q = [&](const char* Qin, char* Qout) {
    i32x4 acc[4] = {};
    const char* rb = Qin + n * QSTR + q * 16;
    char* wb = Qout + n * QSTR + wid * 16 + q * 4;
    f32x4 b1v = *(const f32x4*)(sB1 + wid * 16 + q * 4);   // pre-scaled by S2
    __builtin_amdgcn_s_setprio(1);
#pragma unroll
    for (int st = 0; st < 4; st++)
#pragma unroll
      for (int s = 0; s < 2; s++) {
        i32x4 b = *(const i32x4*)(rb + st * 16 * QSTR + s * 64);
        acc[st] = __builtin_amdgcn_mfma_i32_16x16x64_i8(w1q[s], b, acc[st], 0, 0, 0);
      }
    __builtin_amdgcn_s_setprio(0);
#pragma unroll
    for (int st = 0; st < 4; st++) {
      float r[4];
#pragma unroll
      for (int i = 0; i < 4; i++)
        r[i] = q8pre(fmaf((float)acc[st][i], DQ1S2, b1v[i]));
      *(unsigned*)(wb + st * 16 * QSTR) = pack4(r[0], r[1], r[2], r[3]);
    }
  };

  // L2: i8 MFMA K=64, dequant -> lrelu -> bf16 H3 (for fp32 KRED)
  auto L2Q = [&](const char* Qin, bf16_t* Hout) {
    i32x4 acc[4] = {};
    const char* rb = Qin + n * QSTR + q * 16;
    bf16_t* wb = Hout + n * HSTR + wid * 16 + q * 4;
    f32x4 b2v = *(const f32x4*)(sB2 + wid * 16 + q * 4);
    __builtin_amdgcn_s_setprio(1);
#pragma unroll
    for (int st = 0; st < 4; st++)
#pragma unroll
      for (int s = 0; s < 2; s++) {
        i32x4 b = *(const i32x4*)(rb + st * 16 * QSTR + s * 64);
        acc[st] = __builtin_amdgcn_mfma_i32_16x16x64_i8(w2q[s], b, acc[st], 0, 0, 0);
      }
    __builtin_amdgcn_s_setprio(0);
#pragma unroll
    for (int st = 0; st < 4; st++) {
      bf16x4 o;
#pragma unroll
      for (int i = 0; i < 4; i++) {
        float v = fmaf((float)acc[st][i], DQ2, b2v[i]);
        o[i] = (bf16_t)lrelu(v);
      }
      *(bf16x4*)(wb + st * 16 * HSTR) = o;
    }
  };

  auto KRED = [&](const bf16_t* Hin, const float* wt, const float* ws_, bf16_t* FS) {
    int g = tid >> 6;
    int c = (tid & 63) * 2;
    const bf16_t* kb = Hin + g * 8 * HSTR + c;
    float a0 = 0.f, a1 = 0.f;
#pragma unroll
    for (int k = 0; k < 8; k++) {
      float wk = wt[g * 8 + k];
      unsigned u = *(const unsigned*)(kb + k * HSTR);
      a0 += wk * __uint_as_float(u << 16);
      a1 += wk * __uint_as_float(u & 0xffff0000u);
    }
    float inv = 1.f / ws_[g];
    bf16x2 fo;
    fo[0] = (bf16_t)(a0 * inv);
    fo[1] = (bf16_t)(a1 * inv);
    *(bf16x2*)(FS + g * HSTR + c) = fo;
  };

  auto HEADS = [&](const bf16_t* FS, bf16_t* AR) {
    f32x4 ha = *(const f32x4*)(sBH + wid * 16 + q * 4);
    const bf16_t* rb = FS + n * HSTR + q * 8;
    __builtin_amdgcn_s_setprio(1);
#pragma unroll
    for (int s = 0; s < 4; s++) {
      bf16x8 b = *(const bf16x8*)(rb + s * 32);
      ha = __builtin_amdgcn_mfma_f32_16x16x32_bf16(hdf[s], b, ha, 0, 0, 0);
    }
    __builtin_amdgcn_s_setprio(0);
    if (n < 8) {
      const int base = (wid < 4) ? 64 : 0;    // a-vals high, r-vals low
      bf16x4 o;
      o[0] = (bf16_t)lrelu(ha[0]);
      o[1] = (bf16_t)lrelu(ha[1]);
      o[2] = (bf16_t)lrelu(ha[2]);
      o[3] = (bf16_t)lrelu(ha[3]);
      *(bf16x4*)(AR + n * HSTR + base + (wid & 3) * 16 + q * 4) = o;
    }
  };

  auto FINALS = [&](int tile) {
    if (wid == 0) {
      f32x4 c = *(const f32x4*)sFBv;
      const bf16_t* ab = sFB + l * 8;
      const bf16_t* rb = sAR + n * HSTR + q * 8;
#pragma unroll
      for (int s = 0; s < 4; s++) {
        bf16x8 a = *(const bf16x8*)(ab + s * 512);
        bf16x8 b = *(const bf16x8*)(rb + s * 32);
        c = __builtin_amdgcn_mfma_f32_16x16x32_bf16(a, b, c, 0, 0, 0);
      }
      if (q == 0 && n < 8) {
        float4 o;
        o.x = sigmoidf(c[0]);
        o.y = sigmoidf(c[1]);
        o.z = sigmoidf(c[2]);
        o.w = sigmoidf(c[3]);
        ((float4*)ar_out)[tile * 8 + n] = o;
      }
    }
  };

  // ---- one-time LDS init ----
  for (int i = tid; i < 8 * HSTR; i += 512) {
    sFS[8 * HSTR + i] = (bf16_t)0.f;
    sAR[8 * HSTR + i] = (bf16_t)0.f;
  }
  {
    int e0 = tid * 4;
    int jb = e0 & 7, ll = (e0 >> 3) & 63, s = e0 >> 9;
    int m = ll & 15;
#pragma unroll
    for (int ii = 0; ii < 4; ii++) {
      int k = s * 32 + (ll >> 4) * 8 + jb + ii;
      float v = 0.f;
      if (k < 64)  { if (m < 3) v = wr1g[k * 3 + m]; }
      else         { if (m == 3) v = wa1g[k - 64]; }
      sFB[e0 + ii] = (bf16_t)v;
    }
  }
  if (tid < 128)      sB0[tid] = b0g[tid] * S1_Q;               // pre-scaled for L0
  else if (tid < 256) sB1[tid - 128] = b1g[tid - 128] * S2_Q;   // pre-scaled for L1Q
  else if (tid < 384) sB2[tid - 256] = b2g[tid - 256];
  else { int t = tid - 384; sBH[t] = (t < 64) ? ba0g[t] : br0g[t - 64]; }
  if (tid < 4) sFBv[tid] = (tid < 3) ? br1g[tid] : ba1g[0];
  __syncthreads();

  // ---- dual-stream pipeline (champion schedule) ----
  for (int it = 0; it <= NIT; ++it) {
    const bool a_on = (it < NIT);
    const bool b_on = (it > 0);
    const int tA  = (int)blockIdx.x + (2 * it) * GRID;
    const int tAp = (int)blockIdx.x + (2 * it - 2) * GRID;
    const int tB  = (int)blockIdx.x + (2 * it + 1) * GRID;
    const int tBp = (int)blockIdx.x + (2 * it - 1) * GRID;

    // ---- p1: commitA(sX) | L2B(sQ2->sH3) | finalsA ----
    if (a_on) COMMIT(tA, sX, sWtA);
    if (b_on) L2Q(sQ2, sH3);
    if (b_on) FINALS(tAp);
    __syncthreads();

    // ---- p2: L0A(sX->sQ1) | kredB(sH3->sFS) | sWsA ----
    if (a_on) L0(sX, sQ1);
    if (b_on) KRED(sH3, sWtB, sWsB, sFS);
    if (a_on && tid < 8) {
      float ss = 0.f;
#pragma unroll
      for (int k = 0; k < 8; k++) ss += sWtA[tid * 8 + k];
      sWsA[tid] = ss;
    }
    __syncthreads();

    // ---- p3: L1A(sQ1->sQ2) | headsB(sFS->sAR) ----
    if (a_on) L1Q(sQ1, sQ2);
    if (b_on) HEADS(sFS, sAR);
    __syncthreads();

    // ---- p4: L2A(sQ2->sH3) | commitB(sX) | finalsB ----
    if (a_on) COMMIT(tB, sX, sWtB);
    if (a_on) L2Q(sQ2, sH3);
    if (b_on) FINALS(tBp);
    __syncthreads();

    if (it == NIT) break;   // drain complete (uniform exit)

    // ---- p5: kredA(sH3) | L0B(sX->sQ1) | sWsB ----
    L0(sX, sQ1);
    KRED(sH3, sWtA, sWsA, sFS);
    if (tid < 8) {
      float ss = 0.f;
#pragma unroll
      for (int k = 0; k < 8; k++) ss += sWtB[tid * 8 + k];
      sWsB[tid] = ss;
    }
    __syncthreads();

    // ---- p6: headsA(sFS->sAR) | L1B(sQ1->sQ2) ----
    L1Q(sQ1, sQ2);
    HEADS(sFS, sAR);
    __syncthreads();
  }
}

// ---------------------------------------------------------------------------
// Volume rendering (champion version, separate kernel)
// ---------------------------------------------------------------------------
__global__ __launch_bounds__(512)
void render_kernel(const float* __restrict__ ar, const float* __restrict__ dcam,
                   float* __restrict__ out) {
  int ray = blockIdx.x * 8 + (threadIdx.x >> 6);
  int s = threadIdx.x & 63;
  float4 v = ((const float4*)ar)[ray * 64 + s];
  float alpha = v.w;
  float t = 1.f - alpha + 1e-10f;
  float p = t;
#pragma unroll
  for (int d = 1; d < 64; d <<= 1) {
    float o = __shfl_up(p, d);
    if (s >= d) p *= o;
  }
  float pm1 = __shfl_up(p, 1);
  float T = (s == 0) ? 1.f : pm1;
  float bl = alpha * T;
  float dist = 1.f + 1.25f * dcam[ray * 64 + s];
  float cr = v.x * bl, cg = v.y * bl, cb = v.z * bl, cd = dist * bl, ca = bl;
#pragma unroll
  for (int d = 32; d > 0; d >>= 1) {
    cr += __shfl_xor(cr, d);
    cg += __shfl_xor(cg, d);
    cb += __shfl_xor(cb, d);
    cd += __shfl_xor(cd, d);
    ca += __shfl_xor(ca, d);
  }
  if (s == 0) {
    out[ray * 5 + 0] = cr; out[ray * 5 + 1] = cg; out[ray * 5 + 2] = cb;
    out[ray * 5 + 3] = cd; out[ray * 5 + 4] = ca;
  }
}

// ---------------------------------------------------------------------------
extern "C" void kernel_launch(void* const* d_in, const int* in_sizes, int n_in,
                              void* d_out, int out_size, void* d_ws, size_t ws_size,
                              hipStream_t stream) {
  const float* map_xyz    = (const float*)d_in[0];
  const float* map_feat   = (const float*)d_in[1];
  const int*   ind        = (const int*)d_in[2];
  const float* sample_xyz = (const float*)d_in[3];
  const float* dist_cam   = (const float*)d_in[4];
  const float* W0  = (const float*)d_in[5];
  const float* b0  = (const float*)d_in[6];
  const float* W1  = (const float*)d_in[7];
  const float* b1  = (const float*)d_in[8];
  const float* W2  = (const float*)d_in[9];
  const float* b2  = (const float*)d_in[10];
  const float* Wa0 = (const float*)d_in[11];
  const float* ba0 = (const float*)d_in[12];
  const float* Wa1 = (const float*)d_in[13];
  const float* ba1 = (const float*)d_in[14];
  const float* Wr0 = (const float*)d_in[15];
  const float* br0 = (const float*)d_in[16];
  const float* Wr1 = (const float*)d_in[17];
  const float* br1 = (const float*)d_in[18];

  bf16_t* wpack = (bf16_t*)d_ws;
  char*   wq    = (char*)d_ws + PKQ_OFF;
  float*  ar    = (float*)((char*)d_ws + WS_AR_BYTES);

  pack_weights<<<240, 256, 0, stream>>>(W0, W1, W2, Wa0, Wr0, wpack);
  pack_w12_i8<<<128, 256, 0, stream>>>(W1, W2, wq);
  nerf_main<<<GRID, 512, 0, stream>>>(map_xyz, map_feat, ind, sample_xyz,
                                      b0, b1, b2, ba0, Wa1, ba1, br0, Wr1, br1,
                                      wpack, ar);
  render_kernel<<<256, 512, 0, stream>>>(ar, dist_cam, (float*)d_out);
}